// Round 1
// 432.718 us; speedup vs baseline: 1.0336x; 1.0336x over previous
//
#include <hip/hip_runtime.h>

// Problem constants
#define B_DIM 64
#define S_DIM 128
#define D1    256
#define D2    256
#define KTOT  65536   // D1*D2
#define NOUT  1024

// GEMM geometry: block = 16 W-rows x 4096-k slice.
// Each W row contributes a 16KB CONTIGUOUS HBM stream (vs 4KB before),
// 16384 concurrent streams chip-wide (vs 65536) -> better DRAM page locality.
#define NTILE   16
#define NTILES  (NOUT / NTILE)     // 64
#define KSLICES 16
#define KC      (KTOT / KSLICES)   // 4096 k per block
#define BK      128                // k per staging chunk
#define CHUNKS  (KC / BK)          // 32
#define KSTEPS  (BK / 32)          // 4 mfma k-steps per chunk
#define WPAD    8                  // bf16 pad: row stride 272B -> 2-way (free) bank aliasing

typedef __attribute__((ext_vector_type(8))) short bf16x8;
typedef __attribute__((ext_vector_type(4))) float f32x4;

// Pack two fp32 -> two bf16 (round-half-up)
__device__ inline unsigned pack2bf16(float lo, float hi) {
    unsigned ulo = __float_as_uint(lo);
    unsigned uhi = __float_as_uint(hi);
    ulo = (ulo + 0x8000u) >> 16;
    uhi = (uhi + 0x8000u) & 0xffff0000u;
    return ulo | uhi;
}

// ---------------------------------------------------------------------------
// tp[b, d*256+e] = sum_s ftab[fillers[b,s], d] * rtab[roles[b,s], e]  (bf16)
// Also pre-initializes out[m][n] = bias[n] (gemm accumulates via atomics).
__global__ __launch_bounds__(256) void tp_kernel(const int* __restrict__ fillers,
                                                 const int* __restrict__ roles,
                                                 const float* __restrict__ ftab,
                                                 const float* __restrict__ rtab,
                                                 unsigned short* __restrict__ tp,
                                                 const float* __restrict__ bias,
                                                 float* __restrict__ out) {
    const int b     = blockIdx.x;        // 0..63
    const int dbase = blockIdx.y * 32;   // 8 tiles of 32
    __shared__ float f_sh[S_DIM][32];
    __shared__ int   ridx[S_DIM];
    const int t = threadIdx.x;

    // Fused bias-broadcast init of out: y==0 blocks cover all 64*1024 floats,
    // 4 per thread. Runs before gemm_kernel by stream order.
    if (blockIdx.y == 0) {
        const int i = blockIdx.x * 256 + t;             // 0..16383
        f32x4 bv = *(const f32x4*)(bias + ((i * 4) & (NOUT - 1)));
        *(f32x4*)(out + (size_t)i * 4) = bv;
    }

    const int* fb = fillers + b * S_DIM;
    for (int i = t; i < S_DIM * 32; i += 256) {
        int s = i >> 5, dl = i & 31;
        f_sh[s][dl] = ftab[(long)fb[s] * D1 + dbase + dl];
    }
    if (t < S_DIM) ridx[t] = roles[b * S_DIM + t];
    __syncthreads();

    const int dsub = t >> 6;   // wave-uniform: d = dbase + dsub*8 + dl
    const int et   = t & 63;   // e = et*4
    float acc[8][4];
#pragma unroll
    for (int i = 0; i < 8; ++i)
#pragma unroll
        for (int j = 0; j < 4; ++j) acc[i][j] = 0.f;

    for (int s = 0; s < S_DIM; ++s) {
        const float4 rv = *(const float4*)(rtab + ridx[s] * D2 + et * 4);
        const float4 f0 = *(const float4*)&f_sh[s][dsub * 8];
        const float4 f1 = *(const float4*)&f_sh[s][dsub * 8 + 4];
        float fv[8] = {f0.x, f0.y, f0.z, f0.w, f1.x, f1.y, f1.z, f1.w};
        float rr[4] = {rv.x, rv.y, rv.z, rv.w};
#pragma unroll
        for (int dl = 0; dl < 8; ++dl)
#pragma unroll
            for (int c = 0; c < 4; ++c) acc[dl][c] += fv[dl] * rr[c];
    }

    unsigned short* dst = tp + (size_t)b * KTOT + (size_t)(dbase + dsub * 8) * D2 + et * 4;
#pragma unroll
    for (int dl = 0; dl < 8; ++dl) {
        uint2 pp;
        pp.x = pack2bf16(acc[dl][0], acc[dl][1]);
        pp.y = pack2bf16(acc[dl][2], acc[dl][3]);
        *(uint2*)(dst + (size_t)dl * D2) = pp;
    }
}

// ---------------------------------------------------------------------------
// out[m][n] += sum_k tp[m,k](bf16) * W[n,k].  Block = 16 n-rows x 4096 k.
// W rows are streamed in 16KB contiguous runs per row (32 chunks of 512B),
// packed fp32->bf16 during LDS staging, register prefetch depth 1 overlaps
// HBM latency with the (tiny) MFMA phase. Partials accumulate into out with
// fp32 atomics -> no `part` buffer, no reduce kernel.
__global__ __launch_bounds__(256, 4) void gemm_kernel(const unsigned short* __restrict__ tp,
                                                      const float* __restrict__ W,
                                                      float* __restrict__ out) {
    const int n0    = blockIdx.x * NTILE;   // 0..1008
    const int kbase = blockIdx.y * KC;      // 0..61440
    const int t   = threadIdx.x;
    const int w   = t >> 6;                 // wave 0..3 -> m-tile base w*16
    const int L   = t & 63;
    const int l16 = L & 15;
    const int lq  = L >> 4;                 // 0..3 (k-quad)

    __shared__ unsigned short wlds[NTILE][BK + WPAD];   // 16 x 136 bf16 = 4.3 KB

    // Staging map: thread t -> (row = t>>4, float4-col = t&15), two float4s
    // per thread per chunk. Per wave instruction: 4 rows x 256B contiguous.
    const int srow = t >> 4;
    const int sc4  = t & 15;
    const float* wsrc = W + (size_t)(n0 + srow) * KTOT + kbase + sc4 * 4;

    // A-fragments direct from tp (L2/L3-resident; blocks sharing a k-slice reuse it)
    const unsigned short* tpp = tp + (size_t)(w * 16 + l16) * KTOT + kbase + lq * 8;

    f32x4 acc = {0.f, 0.f, 0.f, 0.f};

    // Prefetch chunk 0
    float4 wr0 = *(const float4*)(wsrc);
    float4 wr1 = *(const float4*)(wsrc + 64);

    for (int bk = 0; bk < CHUNKS; ++bk) {
        // Pack + write current chunk to LDS
        uint2 p0, p1;
        p0.x = pack2bf16(wr0.x, wr0.y);
        p0.y = pack2bf16(wr0.z, wr0.w);
        p1.x = pack2bf16(wr1.x, wr1.y);
        p1.y = pack2bf16(wr1.z, wr1.w);
        *(uint2*)&wlds[srow][sc4 * 4]      = p0;
        *(uint2*)&wlds[srow][sc4 * 4 + 64] = p1;
        __syncthreads();   // chunk bk visible

        // Issue prefetch for chunk bk+1 (overlaps with MFMA phase)
        if (bk + 1 < CHUNKS) {
            const float* wn = wsrc + (size_t)(bk + 1) * BK;
            wr0 = *(const float4*)(wn);
            wr1 = *(const float4*)(wn + 64);
        }

        // Compute: 4 mfma k-steps on chunk bk (1 MFMA per wave per k-step)
#pragma unroll
        for (int kk = 0; kk < KSTEPS; ++kk) {
            bf16x8 a = *(const bf16x8*)(tpp + bk * BK + kk * 32);
            bf16x8 b = *(const bf16x8*)&wlds[l16][kk * 32 + lq * 8];
            acc = __builtin_amdgcn_mfma_f32_16x16x32_bf16(a, b, acc, 0, 0, 0);
        }
        __syncthreads();   // all reads of chunk bk done before overwrite
    }

    // C layout: col = l16 (n), row = lq*4 + r (m within wave's 16-row tile).
    const int m = w * 16 + lq * 4;
    float* op = out + (size_t)m * NOUT + n0 + l16;
#pragma unroll
    for (int r = 0; r < 4; ++r)
        atomicAdd(op + (size_t)r * NOUT, acc[r]);
}

// ---------------------------------------------------------------------------
extern "C" void kernel_launch(void* const* d_in, const int* in_sizes, int n_in,
                              void* d_out, int out_size, void* d_ws, size_t ws_size,
                              hipStream_t stream) {
    const int*   fillers = (const int*)d_in[0];
    const int*   roles   = (const int*)d_in[1];
    const float* ftab    = (const float*)d_in[2];
    const float* rtab    = (const float*)d_in[3];
    const float* W       = (const float*)d_in[4];
    const float* bias    = (const float*)d_in[5];
    float* out = (float*)d_out;

    unsigned short* tp = (unsigned short*)d_ws;   // 64*65536*2 = 8 MB

    hipLaunchKernelGGL(tp_kernel, dim3(B_DIM, 8), dim3(256), 0, stream,
                       fillers, roles, ftab, rtab, tp, bias, out);
    hipLaunchKernelGGL(gemm_kernel, dim3(NTILES, KSLICES), dim3(256), 0, stream,
                       tp, W, out);
}

// Round 2
// 426.486 us; speedup vs baseline: 1.0487x; 1.0146x over previous
//
#include <hip/hip_runtime.h>

// Problem constants
#define B_DIM 64
#define S_DIM 128
#define D1    256
#define D2    256
#define KTOT  65536   // D1*D2
#define NOUT  1024

// GEMM geometry: block = 16 W-rows x 4096-k slice.
// W is staged fp32 into LDS with global_load_lds width=16: each wave
// instruction reads ONE ROW's 1KB contiguous run (64 lanes x 16B), walking
// sequentially down the row -> maximal DRAM burst/page locality, no
// power-of-2 multi-row stride inside an instruction.
#define NTILE   16
#define NTILES  (NOUT / NTILE)     // 64
#define KSLICES 16
#define KC      (KTOT / KSLICES)   // 4096 k per block
#define CK      256                // k per staging chunk (fp32 in LDS)
#define NCHUNK  (KC / CK)          // 16
#define KSTEPS  (CK / 32)          // 8 mfma k-steps per chunk
#define FPAD    4                  // fp32 pad: row stride 260 dwords -> per-phase 2-way (free)

typedef __attribute__((ext_vector_type(8))) short bf16x8;
typedef __attribute__((ext_vector_type(4))) float f32x4;

// Pack two fp32 -> two bf16 (round-half-up)
__device__ inline unsigned pack2bf16(float lo, float hi) {
    unsigned ulo = __float_as_uint(lo);
    unsigned uhi = __float_as_uint(hi);
    ulo = (ulo + 0x8000u) >> 16;
    uhi = (uhi + 0x8000u) & 0xffff0000u;
    return ulo | uhi;
}

// ---------------------------------------------------------------------------
// tp[b, d*256+e] = sum_s ftab[fillers[b,s], d] * rtab[roles[b,s], e]  (bf16)
// Also pre-initializes out[m][n] = bias[n] (gemm accumulates via atomics).
__global__ __launch_bounds__(256) void tp_kernel(const int* __restrict__ fillers,
                                                 const int* __restrict__ roles,
                                                 const float* __restrict__ ftab,
                                                 const float* __restrict__ rtab,
                                                 unsigned short* __restrict__ tp,
                                                 const float* __restrict__ bias,
                                                 float* __restrict__ out) {
    const int b     = blockIdx.x;        // 0..63
    const int dbase = blockIdx.y * 32;   // 8 tiles of 32
    __shared__ float f_sh[S_DIM][32];
    __shared__ int   ridx[S_DIM];
    const int t = threadIdx.x;

    // Fused bias-broadcast init of out: y==0 blocks cover all 64*1024 floats.
    if (blockIdx.y == 0) {
        const int i = blockIdx.x * 256 + t;             // 0..16383
        f32x4 bv = *(const f32x4*)(bias + ((i * 4) & (NOUT - 1)));
        *(f32x4*)(out + (size_t)i * 4) = bv;
    }

    const int* fb = fillers + b * S_DIM;
    for (int i = t; i < S_DIM * 32; i += 256) {
        int s = i >> 5, dl = i & 31;
        f_sh[s][dl] = ftab[(long)fb[s] * D1 + dbase + dl];
    }
    if (t < S_DIM) ridx[t] = roles[b * S_DIM + t];
    __syncthreads();

    const int dsub = t >> 6;   // wave-uniform: d = dbase + dsub*8 + dl
    const int et   = t & 63;   // e = et*4
    float acc[8][4];
#pragma unroll
    for (int i = 0; i < 8; ++i)
#pragma unroll
        for (int j = 0; j < 4; ++j) acc[i][j] = 0.f;

    for (int s = 0; s < S_DIM; ++s) {
        const float4 rv = *(const float4*)(rtab + ridx[s] * D2 + et * 4);
        const float4 f0 = *(const float4*)&f_sh[s][dsub * 8];
        const float4 f1 = *(const float4*)&f_sh[s][dsub * 8 + 4];
        float fv[8] = {f0.x, f0.y, f0.z, f0.w, f1.x, f1.y, f1.z, f1.w};
        float rr[4] = {rv.x, rv.y, rv.z, rv.w};
#pragma unroll
        for (int dl = 0; dl < 8; ++dl)
#pragma unroll
            for (int c = 0; c < 4; ++c) acc[dl][c] += fv[dl] * rr[c];
    }

    unsigned short* dst = tp + (size_t)b * KTOT + (size_t)(dbase + dsub * 8) * D2 + et * 4;
#pragma unroll
    for (int dl = 0; dl < 8; ++dl) {
        uint2 pp;
        pp.x = pack2bf16(acc[dl][0], acc[dl][1]);
        pp.y = pack2bf16(acc[dl][2], acc[dl][3]);
        *(uint2*)(dst + (size_t)dl * D2) = pp;
    }
}

// ---------------------------------------------------------------------------
// out[m][n] += sum_k tp[m,k](bf16) * W[n,k].  Block = 16 n-rows x 4096 k.
// Staging: global_load_lds dwordx4, one row per instruction (1KB contiguous).
// Each wave stages 4 rows per chunk. One __syncthreads per chunk: it drains
// the prefetch issued in the PREVIOUS iteration (vmcnt) and fences the LDS
// reads of the buffer about to be overwritten.
__global__ __launch_bounds__(256, 4) void gemm_kernel(const unsigned short* __restrict__ tp,
                                                      const float* __restrict__ W,
                                                      float* __restrict__ out) {
    const int n0    = blockIdx.x * NTILE;   // 0..1008
    const int kbase = blockIdx.y * KC;      // 0..61440
    const int t   = threadIdx.x;
    const int w   = t >> 6;                 // wave 0..3 -> m-tile base w*16
    const int L   = t & 63;
    const int l16 = L & 15;
    const int lq  = L >> 4;                 // 0..3 (k-quad)

    __shared__ float wbuf[2][NTILE][CK + FPAD];   // 2 x 16 x 260 fp32 = 33.3 KB

    // A-fragments direct from tp (L2/L3-resident; 64 blocks share each k-slice)
    const unsigned short* tpp = tp + (size_t)(w * 16 + l16) * KTOT + kbase + lq * 8;

    // Per-lane global source base for this wave's 4 staging rows.
    const float* wsrc = W + (size_t)(n0 + w * 4) * KTOT + kbase + L * 4;

#define STAGE(ck, buf) do {                                                        \
        _Pragma("unroll")                                                          \
        for (int i_ = 0; i_ < 4; ++i_) {                                           \
            const float* g_ = wsrc + (size_t)i_ * KTOT + (ck) * CK;                \
            __builtin_amdgcn_global_load_lds(                                      \
                (const __attribute__((address_space(1))) unsigned int*)g_,         \
                (__attribute__((address_space(3))) unsigned int*)&wbuf[buf][w * 4 + i_][0], \
                16, 0, 0);                                                         \
        }                                                                          \
    } while (0)

    f32x4 acc = {0.f, 0.f, 0.f, 0.f};

    STAGE(0, 0);
    for (int ck = 0; ck < NCHUNK; ++ck) {
        const int cur = ck & 1;
        __syncthreads();   // drains vmcnt -> wbuf[cur] ready; fences old reads of wbuf[cur^1]

        if (ck + 1 < NCHUNK) STAGE(ck + 1, cur ^ 1);   // async, overlaps compute below

#pragma unroll
        for (int kk = 0; kk < KSTEPS; ++kk) {
            bf16x8 a = *(const bf16x8*)(tpp + ck * CK + kk * 32);
            const float* bp = &wbuf[cur][l16][kk * 32 + lq * 8];
            f32x4 b0 = *(const f32x4*)bp;        // ds_read_b128, per-phase 2-way (free)
            f32x4 b1 = *(const f32x4*)(bp + 4);
            union { unsigned u[4]; bf16x8 v; } bw;
            bw.u[0] = pack2bf16(b0.x, b0.y);
            bw.u[1] = pack2bf16(b0.z, b0.w);
            bw.u[2] = pack2bf16(b1.x, b1.y);
            bw.u[3] = pack2bf16(b1.z, b1.w);
            acc = __builtin_amdgcn_mfma_f32_16x16x32_bf16(a, bw.v, acc, 0, 0, 0);
        }
    }
#undef STAGE

    // C layout: col = l16 (n), row = lq*4 + r (m within wave's 16-row tile).
    const int m = w * 16 + lq * 4;
    float* op = out + (size_t)m * NOUT + n0 + l16;
#pragma unroll
    for (int r = 0; r < 4; ++r)
        atomicAdd(op + (size_t)r * NOUT, acc[r]);
}

// ---------------------------------------------------------------------------
extern "C" void kernel_launch(void* const* d_in, const int* in_sizes, int n_in,
                              void* d_out, int out_size, void* d_ws, size_t ws_size,
                              hipStream_t stream) {
    const int*   fillers = (const int*)d_in[0];
    const int*   roles   = (const int*)d_in[1];
    const float* ftab    = (const float*)d_in[2];
    const float* rtab    = (const float*)d_in[3];
    const float* W       = (const float*)d_in[4];
    const float* bias    = (const float*)d_in[5];
    float* out = (float*)d_out;

    unsigned short* tp = (unsigned short*)d_ws;   // 64*65536*2 = 8 MB

    hipLaunchKernelGGL(tp_kernel, dim3(B_DIM, 8), dim3(256), 0, stream,
                       fillers, roles, ftab, rtab, tp, bias, out);
    hipLaunchKernelGGL(gemm_kernel, dim3(NTILES, KSLICES), dim3(256), 0, stream,
                       tp, W, out);
}

// Round 4
// 425.453 us; speedup vs baseline: 1.0513x; 1.0024x over previous
//
#include <hip/hip_runtime.h>

// Problem constants
#define B_DIM 64
#define S_DIM 128
#define D1    256
#define D2    256
#define KTOT  65536   // D1*D2
#define NOUT  1024

// ---- tp kernel geometry: block = (b, 32 d-rows); R staged via global_load_lds
#define TP_DTILE  32
#define TP_SCHUNK 16                    // s-rows of R per staging chunk
#define TP_NCHUNK (S_DIM / TP_SCHUNK)   // 8

// ---- gemm geometry (round-2 verbatim, harness-verified): 16 W-rows x 4096-k
#define NTILE   16
#define NTILES  (NOUT / NTILE)     // 64
#define KSLICES 16
#define KC      (KTOT / KSLICES)   // 4096 k per block
#define CK      256                // k per staging chunk (fp32 in LDS)
#define NCHUNK  (KC / CK)          // 16
#define KSTEPS  (CK / 32)          // 8 mfma k-steps per chunk
#define FPAD    4

typedef __attribute__((ext_vector_type(8))) short bf16x8;
typedef __attribute__((ext_vector_type(4))) float f32x4;

// Pack two fp32 -> two bf16 (round-half-up)
__device__ inline unsigned pack2bf16(float lo, float hi) {
    unsigned ulo = __float_as_uint(lo);
    unsigned uhi = __float_as_uint(hi);
    ulo = (ulo + 0x8000u) >> 16;
    uhi = (uhi + 0x8000u) & 0xffff0000u;
    return ulo | uhi;
}

// ---------------------------------------------------------------------------
// tp[b, d*256+e] = sum_s ftab[fillers[b,s], d] * rtab[roles[b,s], e]  (bf16)
// R rows staged via global_load_lds into a double-buffered LDS chunk (16 s-rows):
// the per-s rtab gather leaves the critical path; inner loop is pure LDS+FMA.
// Plain __syncthreads pipeline (proven template: compiler drains vmcnt at the
// barrier, so the prefetch issued before compute gets the full phase to land).
// Also pre-initializes out[m][n] = bias[n] (gemm accumulates via atomics).
__global__ __launch_bounds__(256) void tp_kernel(const int* __restrict__ fillers,
                                                 const int* __restrict__ roles,
                                                 const float* __restrict__ ftab,
                                                 const float* __restrict__ rtab,
                                                 unsigned short* __restrict__ tp,
                                                 const float* __restrict__ bias,
                                                 float* __restrict__ out) {
    const int b     = blockIdx.x;               // 0..63
    const int dbase = blockIdx.y * TP_DTILE;    // 8 tiles of 32
    __shared__ float f_sh[S_DIM][TP_DTILE];     // 16 KB
    __shared__ float r_sh[2][TP_SCHUNK][D2];    // 32 KB
    __shared__ int   ridx[S_DIM];
    const int t = threadIdx.x;
    const int w = t >> 6;                       // wave 0..3
    const int L = t & 63;

    // Fused bias-broadcast init of out: y==0 blocks cover all 64*1024 floats.
    if (blockIdx.y == 0) {
        const int i = blockIdx.x * 256 + t;     // 0..16383
        f32x4 bv = *(const f32x4*)(bias + ((i * 4) & (NOUT - 1)));
        *(f32x4*)(out + (size_t)i * 4) = bv;
    }

    if (t < S_DIM) ridx[t] = roles[b * S_DIM + t];
    __syncthreads();   // ridx visible to STAGE_R

    // Wave w stages rows w*4..w*4+3 of the chunk; one 1KB gll per row
    // (wave-uniform LDS base, lane*16B linear dest — gll contract honored).
#define STAGE_R(c, buf) do {                                                       \
        _Pragma("unroll")                                                          \
        for (int i_ = 0; i_ < 4; ++i_) {                                           \
            const int   row_ = ridx[(c) * TP_SCHUNK + w * 4 + i_];                 \
            const float* g_  = rtab + (size_t)row_ * D2 + L * 4;                   \
            __builtin_amdgcn_global_load_lds(                                      \
                (const __attribute__((address_space(1))) unsigned int*)g_,         \
                (__attribute__((address_space(3))) unsigned int*)&r_sh[buf][w * 4 + i_][0], \
                16, 0, 0);                                                         \
        }                                                                          \
    } while (0)

    STAGE_R(0, 0);

    // Fill f_sh: 128 rows x 32 floats, 4 float4 per thread (overlaps gll above)
    const int* fb = fillers + b * S_DIM;
    for (int i = t; i < S_DIM * (TP_DTILE / 4); i += 256) {
        const int s = i >> 3, dq = i & 7;
        *(float4*)&f_sh[s][dq * 4] =
            *(const float4*)&ftab[(size_t)fb[s] * D1 + dbase + dq * 4];
    }
    __syncthreads();   // f_sh ready; gll chunk 0 drained (vmcnt) + visible

    const int et = t & 63;   // e = et*4; d = dbase + w*8 + dl
    float acc[8][4];
#pragma unroll
    for (int i = 0; i < 8; ++i)
#pragma unroll
        for (int j = 0; j < 4; ++j) acc[i][j] = 0.f;

    for (int c = 0; c < TP_NCHUNK; ++c) {
        if (c + 1 < TP_NCHUNK) STAGE_R(c + 1, (c + 1) & 1);   // async prefetch
        const int cb = c & 1;
#pragma unroll
        for (int si = 0; si < TP_SCHUNK; ++si) {
            const int s = c * TP_SCHUNK + si;
            const float4 rv = *(const float4*)&r_sh[cb][si][et * 4];   // 2-way/phase: free
            const float4 f0 = *(const float4*)&f_sh[s][w * 8];         // wave-uniform broadcast
            const float4 f1 = *(const float4*)&f_sh[s][w * 8 + 4];
            float fv[8] = {f0.x, f0.y, f0.z, f0.w, f1.x, f1.y, f1.z, f1.w};
            float rr[4] = {rv.x, rv.y, rv.z, rv.w};
#pragma unroll
            for (int dl = 0; dl < 8; ++dl)
#pragma unroll
                for (int cc = 0; cc < 4; ++cc) acc[dl][cc] += fv[dl] * rr[cc];
        }
        __syncthreads();   // drains gll(c+1); fences reads of buf cb
    }
#undef STAGE_R

    unsigned short* dst = tp + (size_t)b * KTOT + (size_t)(dbase + w * 8) * D2 + et * 4;
#pragma unroll
    for (int dl = 0; dl < 8; ++dl) {
        uint2 pp;
        pp.x = pack2bf16(acc[dl][0], acc[dl][1]);
        pp.y = pack2bf16(acc[dl][2], acc[dl][3]);
        *(uint2*)(dst + (size_t)dl * D2) = pp;
    }
}

// ---------------------------------------------------------------------------
// out[m][n] += sum_k tp[m,k](bf16) * W[n,k].  Block = 16 n-rows x 4096 k.
// Round-2 version VERBATIM (harness-verified): gll dwordx4 staging, one row
// per instruction (1KB contiguous), double-buffered, one __syncthreads per
// chunk (compiler-drained vmcnt doubles as the prefetch fence).
__global__ __launch_bounds__(256, 4) void gemm_kernel(const unsigned short* __restrict__ tp,
                                                      const float* __restrict__ W,
                                                      float* __restrict__ out) {
    const int n0    = blockIdx.x * NTILE;   // 0..1008
    const int kbase = blockIdx.y * KC;      // 0..61440
    const int t   = threadIdx.x;
    const int w   = t >> 6;                 // wave 0..3 -> m-tile base w*16
    const int L   = t & 63;
    const int l16 = L & 15;
    const int lq  = L >> 4;                 // 0..3 (k-quad)

    __shared__ float wbuf[2][NTILE][CK + FPAD];   // 2 x 16 x 260 fp32 = 33.3 KB

    const unsigned short* tpp = tp + (size_t)(w * 16 + l16) * KTOT + kbase + lq * 8;
    const float* wsrc = W + (size_t)(n0 + w * 4) * KTOT + kbase + L * 4;

#define STAGE(ck, buf) do {                                                        \
        _Pragma("unroll")                                                          \
        for (int i_ = 0; i_ < 4; ++i_) {                                           \
            const float* g_ = wsrc + (size_t)i_ * KTOT + (ck) * CK;                \
            __builtin_amdgcn_global_load_lds(                                      \
                (const __attribute__((address_space(1))) unsigned int*)g_,         \
                (__attribute__((address_space(3))) unsigned int*)&wbuf[buf][w * 4 + i_][0], \
                16, 0, 0);                                                         \
        }                                                                          \
    } while (0)

    f32x4 acc = {0.f, 0.f, 0.f, 0.f};

    STAGE(0, 0);
    for (int ck = 0; ck < NCHUNK; ++ck) {
        const int cur = ck & 1;
        __syncthreads();   // drains vmcnt -> wbuf[cur] ready; fences old reads of wbuf[cur^1]

        if (ck + 1 < NCHUNK) STAGE(ck + 1, cur ^ 1);   // async, overlaps compute below

#pragma unroll
        for (int kk = 0; kk < KSTEPS; ++kk) {
            bf16x8 a = *(const bf16x8*)(tpp + ck * CK + kk * 32);
            const float* bp = &wbuf[cur][l16][kk * 32 + lq * 8];
            f32x4 b0 = *(const f32x4*)bp;        // ds_read_b128, per-phase 2-way (free)
            f32x4 b1 = *(const f32x4*)(bp + 4);
            union { unsigned u[4]; bf16x8 v; } bw;
            bw.u[0] = pack2bf16(b0.x, b0.y);
            bw.u[1] = pack2bf16(b0.z, b0.w);
            bw.u[2] = pack2bf16(b1.x, b1.y);
            bw.u[3] = pack2bf16(b1.z, b1.w);
            acc = __builtin_amdgcn_mfma_f32_16x16x32_bf16(a, bw.v, acc, 0, 0, 0);
        }
        __syncthreads();   // all reads of chunk ck done before overwrite
    }
#undef STAGE

    // C layout: col = l16 (n), row = lq*4 + r (m within wave's 16-row tile).
    const int m = w * 16 + lq * 4;
    float* op = out + (size_t)m * NOUT + n0 + l16;
#pragma unroll
    for (int r = 0; r < 4; ++r)
        atomicAdd(op + (size_t)r * NOUT, acc[r]);
}

// ---------------------------------------------------------------------------
extern "C" void kernel_launch(void* const* d_in, const int* in_sizes, int n_in,
                              void* d_out, int out_size, void* d_ws, size_t ws_size,
                              hipStream_t stream) {
    const int*   fillers = (const int*)d_in[0];
    const int*   roles   = (const int*)d_in[1];
    const float* ftab    = (const float*)d_in[2];
    const float* rtab    = (const float*)d_in[3];
    const float* W       = (const float*)d_in[4];
    const float* bias    = (const float*)d_in[5];
    float* out = (float*)d_out;

    unsigned short* tp = (unsigned short*)d_ws;   // 64*65536*2 = 8 MB

    hipLaunchKernelGGL(tp_kernel, dim3(B_DIM, 8), dim3(256), 0, stream,
                       fillers, roles, ftab, rtab, tp, bias, out);
    hipLaunchKernelGGL(gemm_kernel, dim3(NTILES, KSLICES), dim3(256), 0, stream,
                       tp, W, out);
}

// Round 5
// 419.581 us; speedup vs baseline: 1.0660x; 1.0140x over previous
//
#include <hip/hip_runtime.h>

// Problem constants
#define B_DIM 64
#define S_DIM 128
#define D1    256
#define D2    256
#define KTOT  65536   // D1*D2
#define NOUT  1024

// ---- tp kernel geometry: block = (b, 32 d-rows); R staged via global_load_lds
#define TP_DTILE  32
#define TP_SCHUNK 16                    // s-rows of R per staging chunk
#define TP_NCHUNK (S_DIM / TP_SCHUNK)   // 8

// ---- gemm geometry: 16 W-rows x 4096-k slice per block.
// Grid = (ks, nt): linear id = ks + 16*nt -> xcd = id%8 = ks%8, so all 64
// blocks sharing a tp k-slice land on ONE XCD; the 512KB slice stays in that
// XCD's 4MB L2 (tp HBM traffic ~64MB -> ~8MB).
#define NTILE   16
#define NTILES  (NOUT / NTILE)     // 64
#define KSLICES 16
#define KC      (KTOT / KSLICES)   // 4096 k per block
#define CK      256                // k per staging chunk (fp32 in LDS)
#define NCHUNK  (KC / CK)          // 16
#define KSTEPS  (CK / 32)          // 8 mfma k-steps per chunk
#define FPAD    4

typedef __attribute__((ext_vector_type(8))) short bf16x8;
typedef __attribute__((ext_vector_type(4))) float f32x4;

// Pack two fp32 -> two bf16 (round-half-up)
__device__ inline unsigned pack2bf16(float lo, float hi) {
    unsigned ulo = __float_as_uint(lo);
    unsigned uhi = __float_as_uint(hi);
    ulo = (ulo + 0x8000u) >> 16;
    uhi = (uhi + 0x8000u) & 0xffff0000u;
    return ulo | uhi;
}

// ---------------------------------------------------------------------------
// tp[b, d*256+e] = sum_s ftab[fillers[b,s], d] * rtab[roles[b,s], e]  (bf16)
// (round-4 verbatim, harness-verified)
__global__ __launch_bounds__(256) void tp_kernel(const int* __restrict__ fillers,
                                                 const int* __restrict__ roles,
                                                 const float* __restrict__ ftab,
                                                 const float* __restrict__ rtab,
                                                 unsigned short* __restrict__ tp,
                                                 const float* __restrict__ bias,
                                                 float* __restrict__ out) {
    const int b     = blockIdx.x;               // 0..63
    const int dbase = blockIdx.y * TP_DTILE;    // 8 tiles of 32
    __shared__ float f_sh[S_DIM][TP_DTILE];     // 16 KB
    __shared__ float r_sh[2][TP_SCHUNK][D2];    // 32 KB
    __shared__ int   ridx[S_DIM];
    const int t = threadIdx.x;
    const int w = t >> 6;                       // wave 0..3
    const int L = t & 63;

    // Fused bias-broadcast init of out: y==0 blocks cover all 64*1024 floats.
    if (blockIdx.y == 0) {
        const int i = blockIdx.x * 256 + t;     // 0..16383
        f32x4 bv = *(const f32x4*)(bias + ((i * 4) & (NOUT - 1)));
        *(f32x4*)(out + (size_t)i * 4) = bv;
    }

    if (t < S_DIM) ridx[t] = roles[b * S_DIM + t];
    __syncthreads();   // ridx visible to STAGE_R

    // Wave w stages rows w*4..w*4+3 of the chunk; one 1KB gll per row.
#define STAGE_R(c, buf) do {                                                       \
        _Pragma("unroll")                                                          \
        for (int i_ = 0; i_ < 4; ++i_) {                                           \
            const int   row_ = ridx[(c) * TP_SCHUNK + w * 4 + i_];                 \
            const float* g_  = rtab + (size_t)row_ * D2 + L * 4;                   \
            __builtin_amdgcn_global_load_lds(                                      \
                (const __attribute__((address_space(1))) unsigned int*)g_,         \
                (__attribute__((address_space(3))) unsigned int*)&r_sh[buf][w * 4 + i_][0], \
                16, 0, 0);                                                         \
        }                                                                          \
    } while (0)

    STAGE_R(0, 0);

    // Fill f_sh: 128 rows x 32 floats, 4 float4 per thread (overlaps gll above)
    const int* fb = fillers + b * S_DIM;
    for (int i = t; i < S_DIM * (TP_DTILE / 4); i += 256) {
        const int s = i >> 3, dq = i & 7;
        *(float4*)&f_sh[s][dq * 4] =
            *(const float4*)&ftab[(size_t)fb[s] * D1 + dbase + dq * 4];
    }
    __syncthreads();   // f_sh ready; gll chunk 0 drained (vmcnt) + visible

    const int et = t & 63;   // e = et*4; d = dbase + w*8 + dl
    float acc[8][4];
#pragma unroll
    for (int i = 0; i < 8; ++i)
#pragma unroll
        for (int j = 0; j < 4; ++j) acc[i][j] = 0.f;

    for (int c = 0; c < TP_NCHUNK; ++c) {
        if (c + 1 < TP_NCHUNK) STAGE_R(c + 1, (c + 1) & 1);   // async prefetch
        const int cb = c & 1;
#pragma unroll
        for (int si = 0; si < TP_SCHUNK; ++si) {
            const int s = c * TP_SCHUNK + si;
            const float4 rv = *(const float4*)&r_sh[cb][si][et * 4];
            const float4 f0 = *(const float4*)&f_sh[s][w * 8];      // wave-uniform broadcast
            const float4 f1 = *(const float4*)&f_sh[s][w * 8 + 4];
            float fv[8] = {f0.x, f0.y, f0.z, f0.w, f1.x, f1.y, f1.z, f1.w};
            float rr[4] = {rv.x, rv.y, rv.z, rv.w};
#pragma unroll
            for (int dl = 0; dl < 8; ++dl)
#pragma unroll
                for (int cc = 0; cc < 4; ++cc) acc[dl][cc] += fv[dl] * rr[cc];
        }
        __syncthreads();   // drains gll(c+1); fences reads of buf cb
    }
#undef STAGE_R

    unsigned short* dst = tp + (size_t)b * KTOT + (size_t)(dbase + w * 8) * D2 + et * 4;
#pragma unroll
    for (int dl = 0; dl < 8; ++dl) {
        uint2 pp;
        pp.x = pack2bf16(acc[dl][0], acc[dl][1]);
        pp.y = pack2bf16(acc[dl][2], acc[dl][3]);
        *(uint2*)(dst + (size_t)dl * D2) = pp;
    }
}

// ---------------------------------------------------------------------------
// out[m][n] += sum_k tp[m,k](bf16) * W[n,k].  Block = 16 n-rows x 4096 k.
// Proven __syncthreads double-buffer template (round-2). Changes this round:
// (1) grid axes swapped -> same-ks blocks co-locate on one XCD (tp L2-resident),
// (2) A-fragment loads hoisted to right after the barrier so their L2 latency
//     overlaps the 16-gll staging issue.
__global__ __launch_bounds__(256, 4) void gemm_kernel(const unsigned short* __restrict__ tp,
                                                      const float* __restrict__ W,
                                                      float* __restrict__ out) {
    const int ks    = blockIdx.x;           // 0..15  (xcd = (ks + 16*nt)%8 = ks%8)
    const int nt    = blockIdx.y;           // 0..63
    const int n0    = nt * NTILE;
    const int kbase = ks * KC;
    const int t   = threadIdx.x;
    const int w   = t >> 6;                 // wave 0..3 -> m-tile base w*16
    const int L   = t & 63;
    const int l16 = L & 15;
    const int lq  = L >> 4;                 // 0..3 (k-quad)

    __shared__ float wbuf[2][NTILE][CK + FPAD];   // 2 x 16 x 260 fp32 = 33.3 KB

    const unsigned short* tpp = tp + (size_t)(w * 16 + l16) * KTOT + kbase + lq * 8;
    const float* wsrc = W + (size_t)(n0 + w * 4) * KTOT + kbase + L * 4;

#define STAGE(ck, buf) do {                                                        \
        _Pragma("unroll")                                                          \
        for (int i_ = 0; i_ < 4; ++i_) {                                           \
            const float* g_ = wsrc + (size_t)i_ * KTOT + (ck) * CK;                \
            __builtin_amdgcn_global_load_lds(                                      \
                (const __attribute__((address_space(1))) unsigned int*)g_,         \
                (__attribute__((address_space(3))) unsigned int*)&wbuf[buf][w * 4 + i_][0], \
                16, 0, 0);                                                         \
        }                                                                          \
    } while (0)

    f32x4 acc = {0.f, 0.f, 0.f, 0.f};

    STAGE(0, 0);
    for (int ck = 0; ck < NCHUNK; ++ck) {
        const int cur = ck & 1;
        __syncthreads();   // drains vmcnt -> wbuf[cur] ready; fences old reads of wbuf[cur^1]

        // A-fragments for chunk ck, issued before the staging burst: their
        // L2-hit latency overlaps the gll issue + first ds_reads.
        bf16x8 a[KSTEPS];
#pragma unroll
        for (int kk = 0; kk < KSTEPS; ++kk)
            a[kk] = *(const bf16x8*)(tpp + ck * CK + kk * 32);

        if (ck + 1 < NCHUNK) STAGE(ck + 1, cur ^ 1);   // async, overlaps compute below

#pragma unroll
        for (int kk = 0; kk < KSTEPS; ++kk) {
            const float* bp = &wbuf[cur][l16][kk * 32 + lq * 8];
            f32x4 b0 = *(const f32x4*)bp;        // ds_read_b128, per-phase 2-way (free)
            f32x4 b1 = *(const f32x4*)(bp + 4);
            union { unsigned u[4]; bf16x8 v; } bw;
            bw.u[0] = pack2bf16(b0.x, b0.y);
            bw.u[1] = pack2bf16(b0.z, b0.w);
            bw.u[2] = pack2bf16(b1.x, b1.y);
            bw.u[3] = pack2bf16(b1.z, b1.w);
            acc = __builtin_amdgcn_mfma_f32_16x16x32_bf16(a[kk], bw.v, acc, 0, 0, 0);
        }
        __syncthreads();   // all reads of chunk ck done before overwrite
    }
#undef STAGE

    // C layout: col = l16 (n), row = lq*4 + r (m within wave's 16-row tile).
    const int m = w * 16 + lq * 4;
    float* op = out + (size_t)m * NOUT + n0 + l16;
#pragma unroll
    for (int r = 0; r < 4; ++r)
        atomicAdd(op + (size_t)r * NOUT, acc[r]);
}

// ---------------------------------------------------------------------------
extern "C" void kernel_launch(void* const* d_in, const int* in_sizes, int n_in,
                              void* d_out, int out_size, void* d_ws, size_t ws_size,
                              hipStream_t stream) {
    const int*   fillers = (const int*)d_in[0];
    const int*   roles   = (const int*)d_in[1];
    const float* ftab    = (const float*)d_in[2];
    const float* rtab    = (const float*)d_in[3];
    const float* W       = (const float*)d_in[4];
    const float* bias    = (const float*)d_in[5];
    float* out = (float*)d_out;

    unsigned short* tp = (unsigned short*)d_ws;   // 64*65536*2 = 8 MB

    hipLaunchKernelGGL(tp_kernel, dim3(B_DIM, 8), dim3(256), 0, stream,
                       fillers, roles, ftab, rtab, tp, bias, out);
    hipLaunchKernelGGL(gemm_kernel, dim3(KSLICES, NTILES), dim3(256), 0, stream,
                       tp, W, out);
}